// Round 3
// baseline (1018.261 us; speedup 1.0000x reference)
//
#include <hip/hip_runtime.h>
#include <hip/hip_bf16.h>

#define B_ 32
#define P_ 1024
#define F_ 512
#define C_ 512

#define BM 128
#define BN 128
#define BK 64
#define LDK 72   // padded K stride (halfwords); rows stay 16B aligned (144 B)

typedef unsigned short u16;
typedef unsigned int   u32;
typedef __bf16 bf16x8 __attribute__((ext_vector_type(8)));
typedef float  f32x4  __attribute__((ext_vector_type(4)));

union U4 { uint4 v; u16 h[8]; u32 w[4]; };

__device__ __forceinline__ u16 f2bf(float f) {
  u32 x = __builtin_bit_cast(u32, f);
  return (u16)((x + 0x7FFFu + ((x >> 16) & 1u)) >> 16);   // RNE
}
__device__ __forceinline__ u32 pack2(float a, float b) {
  return (u32)f2bf(a) | ((u32)f2bf(b) << 16);
}

__device__ __forceinline__ f32x4 mfma16(bf16x8 a, bf16x8 b, f32x4 c) {
  return __builtin_amdgcn_mfma_f32_16x16x32_bf16(a, b, c, 0, 0, 0);
}

// XOR swizzle: element (m,k) lives at lds[m*LDK + (k ^ (m & 56))].
// Keeps 8-halfword fragment groups contiguous & 16B aligned for ds_read_b128.
__device__ __forceinline__ int swz(int m, int k) { return m * LDK + (k ^ (m & 56)); }

// ---------------------------------------------------------------- out0 / out2
// x: f32 [B,P,F] -> f32 copy (out0) and 3x broadcast (out2). Pure BW.
__global__ __launch_bounds__(256) void copy_kernel(const uint4* __restrict__ x,
                                                   uint4* __restrict__ out0,
                                                   uint4* __restrict__ out2) {
  int i = blockIdx.x * 256 + threadIdx.x;       // float4 group, [0, B*P*F/4)
  uint4 v = x[i];
  out0[i] = v;
  int b = i >> 17;                              // P*F/4 = 131072 groups per graph
  int r = i & 131071;
  uint4* o2 = out2 + ((size_t)b * 3 * 131072 + r);
  o2[0] = v; o2[131072] = v; o2[2 * 131072] = v;
}

// ---------------------------------------------------------------- out3 gather/transpose
// out3[b,c,p] = evec[b,p, round(c*step)]  (f32 in, f32 out)
__global__ __launch_bounds__(256) void sel_kernel(const float* __restrict__ evec,
                                                  const int* __restrict__ nv,
                                                  float* __restrict__ out3) {
  const int b  = blockIdx.z;
  const int c0 = blockIdx.y * 64;
  const int p0 = blockIdx.x * 64;
  const int N  = nv[b];
  const float step = (float)(N - 1) / 511.0f;               // (C-1)=511, f32 like jnp
  const int base  = (int)rintf((float)c0 * step);
  const int basea = base & ~3;                               // float4-aligned window start
  __shared__ float tile[64][145];                            // 144-col window, odd stride
  const int t = threadIdx.x;

  for (int it = t; it < 64 * 36; it += 256) {                // 64 rows x 36 groups of 4
    int row = it / 36, g = it % 36;
    int colg = basea + g * 4;
    const float* src = evec + ((size_t)b * P_ + (p0 + row)) * P_ + colg;
    if (colg + 4 <= P_) {
      float4 v = *(const float4*)src;
      tile[row][g * 4 + 0] = v.x;
      tile[row][g * 4 + 1] = v.y;
      tile[row][g * 4 + 2] = v.z;
      tile[row][g * 4 + 3] = v.w;
    } else {
      #pragma unroll
      for (int j = 0; j < 4; ++j)
        tile[row][g * 4 + j] = (colg + j < P_) ? src[j] : 0.f;
    }
  }
  __syncthreads();

  for (int it = t; it < 64 * 32; it += 256) {                // 64 c x 32 p-pairs
    int cl = it >> 5, pp = it & 31;
    int c = c0 + cl;
    int col = (int)rintf((float)c * step) - basea;           // < 144
    float2 val = make_float2(tile[pp * 2][col], tile[pp * 2 + 1][col]);
    *(float2*)(out3 + ((size_t)b * C_ + c) * P_ + p0 + pp * 2) = val;
  }
}

// ---------------------------------------------------------------- shared MMA inner tile
__device__ __forceinline__ void mma_tile(const u16* lA, const u16* lB,
                                         int wm, int wn, int lrow, int quad,
                                         f32x4 acc[4][4]) {
  #pragma unroll
  for (int ks = 0; ks < 2; ++ks) {
    const int k0 = ks * 32 + quad * 8;
    bf16x8 af[4], bfr[4];
    #pragma unroll
    for (int mi = 0; mi < 4; ++mi) {
      int m = wm + mi * 16 + lrow;
      af[mi] = *(const bf16x8*)(lA + swz(m, k0));
    }
    #pragma unroll
    for (int ni = 0; ni < 4; ++ni) {
      int n = wn + ni * 16 + lrow;
      bfr[ni] = *(const bf16x8*)(lB + swz(n, k0));
    }
    #pragma unroll
    for (int mi = 0; mi < 4; ++mi)
      #pragma unroll
      for (int ni = 0; ni < 4; ++ni)
        acc[mi][ni] = mfma16(af[mi], bfr[ni], acc[mi][ni]);
  }
}

// ---------------------------------------------------------------- GEMM1: gft = E^T X
// A[k=n][m=p] = evec[b][n][p] (f32, transpose stage), B[k=n][f] = x[b][n][f] (f32)
// Output gft kept bf16 in workspace (feeds GEMM2's B operand).
__global__ __launch_bounds__(256) void gemm1(const float* __restrict__ evec,
                                             const float* __restrict__ x,
                                             const int* __restrict__ nv,
                                             u16* __restrict__ gft) {
  const int b = blockIdx.z, m0 = blockIdx.x * BM, f0 = blockIdx.y * BN;
  const int N = nv[b];
  __shared__ __align__(16) u16 lA[BM * LDK];
  __shared__ __align__(16) u16 lB[BN * LDK];
  f32x4 acc[4][4] = {};
  const int t = threadIdx.x;
  const int lane = t & 63, w = t >> 6;
  const int wm = (w >> 1) * 64, wn = (w & 1) * 64;
  const int lrow = lane & 15, quad = lane >> 4;
  const int kl = t >> 5;                                     // [0,8)
  const int mg = (t & 31) * 4;                               // [0,128), 4-col groups

  for (int kk = 0; kk < N; kk += BK) {
    // stage A (transpose): 64 k-rows x 128 m-cols; rows >= N are zero in data
    #pragma unroll
    for (int r = 0; r < 8; ++r) {
      int k = r * 8 + kl;
      float4 v = *(const float4*)(evec + ((size_t)b * P_ + kk + k) * P_ + m0 + mg);
      lA[swz(mg + 0, k)] = f2bf(v.x);
      lA[swz(mg + 1, k)] = f2bf(v.y);
      lA[swz(mg + 2, k)] = f2bf(v.z);
      lA[swz(mg + 3, k)] = f2bf(v.w);
    }
    // stage B (transpose): 64 k-rows x 128 f-cols
    #pragma unroll
    for (int r = 0; r < 8; ++r) {
      int k = r * 8 + kl;
      float4 v = *(const float4*)(x + ((size_t)b * P_ + kk + k) * F_ + f0 + mg);
      lB[swz(mg + 0, k)] = f2bf(v.x);
      lB[swz(mg + 1, k)] = f2bf(v.y);
      lB[swz(mg + 2, k)] = f2bf(v.z);
      lB[swz(mg + 3, k)] = f2bf(v.w);
    }
    __syncthreads();
    mma_tile(lA, lB, wm, wn, lrow, quad, acc);
    __syncthreads();
  }

  #pragma unroll
  for (int mi = 0; mi < 4; ++mi)
    #pragma unroll
    for (int ni = 0; ni < 4; ++ni) {
      int row = m0 + wm + mi * 16 + quad * 4;
      int col = f0 + wn + ni * 16 + lrow;
      u16* dst = gft + ((size_t)b * P_ + row) * F_ + col;
      #pragma unroll
      for (int r = 0; r < 4; ++r) dst[(size_t)r * F_] = f2bf(acc[mi][ni][r]);
    }
}

// ---------------------------------------------------------------- GEMM2: U_k = E[:,lo:hi) gft[lo:hi)
// A[m=p][k] = evec[b][p][k] (f32, direct stage, k-masked); B[k][f] = gft (bf16 ws, transpose)
// Output out1 = x_updated [B,3,P,F] in f32.
__global__ __launch_bounds__(256) void gemm2(const float* __restrict__ evec,
                                             const u16* __restrict__ gft,
                                             const int* __restrict__ nv,
                                             float* __restrict__ out1) {
  const int b = blockIdx.z / 3, slab = blockIdx.z % 3;
  const int m0 = blockIdx.x * BM, f0 = blockIdx.y * BN;
  const int N = nv[b];
  const float t1 = (float)N * 0.1f;                          // match jnp f32 order
  const int s1 = (int)ceilf(t1);
  const int s2 = (int)ceilf(t1 * 2.0f);
  const int lo = (slab == 0) ? 0 : ((slab == 1) ? s1 : s1 + s2);
  const int hi = (slab == 0) ? s1 : ((slab == 1) ? s1 + s2 : N);

  __shared__ __align__(16) u16 lA[BM * LDK];
  __shared__ __align__(16) u16 lB[BN * LDK];
  f32x4 acc[4][4] = {};
  const int t = threadIdx.x;
  const int lane = t & 63, w = t >> 6;
  const int wm = (w >> 1) * 64, wn = (w & 1) * 64;
  const int lrow = lane & 15, quad = lane >> 4;

  for (int kk = (lo & ~(BK - 1)); kk < hi; kk += BK) {
    // stage A (direct [m][k]): f32 loads along k, mask to [lo,hi)
    {
      int mrow = t >> 4;                                     // [0,16), +16 per pass
      int kq = (t & 15) * 4;                                 // [0,64)
      #pragma unroll
      for (int r = 0; r < 8; ++r) {
        int m = r * 16 + mrow;
        int kb = kk + kq;
        const float* src = evec + ((size_t)b * P_ + m0 + m) * P_ + kb;
        float4 v;
        if (kb >= lo && kb + 4 <= hi) {
          v = *(const float4*)src;
        } else {
          v.x = (kb + 0 >= lo && kb + 0 < hi) ? src[0] : 0.f;
          v.y = (kb + 1 >= lo && kb + 1 < hi) ? src[1] : 0.f;
          v.z = (kb + 2 >= lo && kb + 2 < hi) ? src[2] : 0.f;
          v.w = (kb + 3 >= lo && kb + 3 < hi) ? src[3] : 0.f;
        }
        u32* dst = (u32*)(lA + swz(m, kq));                  // 8B aligned group of 4
        dst[0] = pack2(v.x, v.y);
        dst[1] = pack2(v.z, v.w);
      }
    }
    // stage B (transpose): gft (bf16) rows k -> lB[f][k]; zero rows outside [lo,hi)
    {
      int kl = t >> 4, fl = (t & 15) * 8;
      #pragma unroll
      for (int r = 0; r < 4; ++r) {
        int k = r * 16 + kl;
        int kb = kk + k;
        U4 u;
        if (kb >= lo && kb < hi) u.v = *(const uint4*)(gft + ((size_t)b * P_ + kb) * F_ + f0 + fl);
        else                     u.v = make_uint4(0, 0, 0, 0);
        #pragma unroll
        for (int j = 0; j < 8; ++j) lB[swz(fl + j, k)] = u.h[j];
      }
    }
    __syncthreads();
    mma_tile(lA, lB, wm, wn, lrow, quad, acc);
    __syncthreads();
  }

  #pragma unroll
  for (int mi = 0; mi < 4; ++mi)
    #pragma unroll
    for (int ni = 0; ni < 4; ++ni) {
      int row = m0 + wm + mi * 16 + quad * 4;
      int col = f0 + wn + ni * 16 + lrow;
      float* dst = out1 + (((size_t)b * 3 + slab) * P_ + row) * F_ + col;
      #pragma unroll
      for (int r = 0; r < 4; ++r) dst[(size_t)r * F_] = acc[mi][ni][r];
    }
}

// ----------------------------------------------------------------
extern "C" void kernel_launch(void* const* d_in, const int* in_sizes, int n_in,
                              void* d_out, int out_size, void* d_ws, size_t ws_size,
                              hipStream_t stream) {
  // Bind inputs by size (defensive against ordering surprises).
  const float* x  = nullptr;   // f32 [B,P,F]  = 16,777,216 elems
  const float* ev = nullptr;   // f32 [B,P,P]  = 33,554,432 elems
  const int*   nv = nullptr;   // i32 [B]      = 32 elems
  for (int i = 0; i < n_in; ++i) {
    if      (in_sizes[i] == B_)            nv = (const int*)d_in[i];
    else if (in_sizes[i] == B_ * P_ * P_)  ev = (const float*)d_in[i];
    else if (in_sizes[i] == B_ * P_ * F_)  x  = (const float*)d_in[i];
  }

  float* out = (float*)d_out;              // f32 outputs, concatenated flat
  const size_t S0 = (size_t)B_ * P_ * F_;  // 16,777,216
  float* out0 = out;                       // n_level_feat    [B,P,F]
  float* out1 = out + S0;                  // x_updated       [B,3,P,F]
  float* out2 = out + 4 * S0;              // original_x      [B,3,P,F]
  float* out3 = out + 7 * S0;              // updated_evectors[B,C,P]
  u16* gft  = (u16*)d_ws;                  // bf16 [B,P,F] scratch (33.5 MB)

  copy_kernel<<<16384, 256, 0, stream>>>((const uint4*)x, (uint4*)out0, (uint4*)out2);
  sel_kernel<<<dim3(16, 8, 32), 256, 0, stream>>>(ev, nv, out3);
  gemm1<<<dim3(8, 4, 32), 256, 0, stream>>>(ev, x, nv, gft);
  gemm2<<<dim3(8, 4, 96), 256, 0, stream>>>(ev, gft, nv, out1);
}